// Round 10
// baseline (289.091 us; speedup 1.0000x reference)
//
#include <hip/hip_runtime.h>
#include <math.h>

// KGVAE: 2-layer RelGraphConv (bdd) + reparameterize, R20.
// = R18b (263.4us champion: dst-CSR edge walk, 1 node/wave, gload_lds staging,
//   f16 packed FMA, MFMA self-loop GEMMs)
// + edge2 output-half split: each wave computes 64 of 128 out cols (1 uint4
//   weight load + 4 pk_fma per edge). 2x grid, halves interleaved by blockIdx
//   parity -> 100K thin waves (R19 showed wave count > per-wave overhead).
// ws: h1bh | h1h | h2bh | embh | w1h(f16) | w2h(f16) | pkA | pkB | norm_s
//     | deg fil | off | bsum

typedef __attribute__((ext_vector_type(8))) short bf16x8;
typedef __attribute__((ext_vector_type(4))) float f32x4;
typedef __attribute__((ext_vector_type(2))) _Float16 h2;

__device__ __forceinline__ int bcasti(int v, int l) { return __builtin_amdgcn_readlane(v, l); }
__device__ __forceinline__ float bcastf(float v, int l) {
    return __int_as_float(__builtin_amdgcn_readlane(__float_as_int(v), l));
}
__device__ __forceinline__ unsigned short f2bf(float f) {  // RTN bf16
    unsigned u = __float_as_uint(f);
    return (unsigned short)((u + 0x7FFFu + ((u >> 16) & 1u)) >> 16);
}
__device__ __forceinline__ unsigned short f2h(float f) {   // RN f16
    return __builtin_bit_cast(unsigned short, (_Float16)f);
}
__device__ __forceinline__ float bfs(unsigned short s) { return __uint_as_float((unsigned)s << 16); }
__device__ __forceinline__ h2 uh2(unsigned u) { return __builtin_bit_cast(h2, u); }

// direct global->LDS 16B: LDS dest = base + lane*16 (HW), global addr per-lane
__device__ __forceinline__ void gload_lds16(const void* g, void* l) {
    __builtin_amdgcn_global_load_lds(
        (const __attribute__((address_space(1))) unsigned int*)g,
        (__attribute__((address_space(3))) unsigned int*)l, 16, 0, 0);
}

__global__ void hist(const int* __restrict__ dst, int* __restrict__ deg, int e) {
    int i = blockIdx.x * blockDim.x + threadIdx.x;
    if (i < e) atomicAdd(&deg[dst[i]], 1);
}

__global__ void scan_part(const int* __restrict__ deg, int* __restrict__ bsum, int n) {
    __shared__ int sm[256];
    int t = threadIdx.x, g = blockIdx.x * 256 + t;
    sm[t] = (g < n) ? deg[g] : 0;
    __syncthreads();
    for (int d = 128; d > 0; d >>= 1) {
        if (t < d) sm[t] += sm[t + d];
        __syncthreads();
    }
    if (t == 0) bsum[blockIdx.x] = sm[0];
}

__global__ void scan_bsum(int* __restrict__ bsum, int* __restrict__ off, int nb, int n) {
    __shared__ int sm[256];
    int t = threadIdx.x;
    int v = (t < nb) ? bsum[t] : 0;
    sm[t] = v;
    __syncthreads();
    for (int d = 1; d < 256; d <<= 1) {
        int u = (t >= d) ? sm[t - d] : 0;
        __syncthreads();
        sm[t] += u;
        __syncthreads();
    }
    if (t < nb) bsum[t] = sm[t] - v;
    if (t == 255) off[n] = sm[255];
}

__global__ void scan_write(const int* __restrict__ deg, const int* __restrict__ bsum,
                           int* __restrict__ off, int n) {
    __shared__ int sm[256];
    int t = threadIdx.x, g = blockIdx.x * 256 + t;
    int v = (g < n) ? deg[g] : 0;
    sm[t] = v;
    __syncthreads();
    for (int d = 1; d < 256; d <<= 1) {
        int u = (t >= d) ? sm[t - d] : 0;
        __syncthreads();
        sm[t] += u;
        __syncthreads();
    }
    if (g < n) off[g] = bsum[blockIdx.x] + sm[t] - v;
}

__global__ void scatter_pack(const int* __restrict__ src, const int* __restrict__ dst,
                             const int* __restrict__ rel, const float* __restrict__ norm,
                             const int* __restrict__ h_ids, const int* __restrict__ off,
                             int* __restrict__ fil, unsigned* __restrict__ packA,
                             unsigned* __restrict__ packB, float* __restrict__ norm_s, int e) {
    int i = blockIdx.x * blockDim.x + threadIdx.x;
    if (i >= e) return;
    int d = dst[i];
    int p = off[d] + atomicAdd(&fil[d], 1);
    unsigned rhi = (unsigned)rel[i] << 16;
    int s = src[i];
    packA[p] = (unsigned)h_ids[s] | rhi;
    packB[p] = (unsigned)s | rhi;
    norm_s[p] = norm[i];
}

// fused conversion: w1,w2 -> f16 ; emb -> bf16
__global__ void cvt_all(const float* __restrict__ w1, const float* __restrict__ w2,
                        const float* __restrict__ emb, unsigned short* __restrict__ w1h,
                        unsigned short* __restrict__ w2h, unsigned short* __restrict__ embh,
                        int n1, int n2, int ne) {
    int i = blockIdx.x * blockDim.x + threadIdx.x;
    if (i < n1) w1h[i] = f2h(w1[i]);
    else if (i < n1 + n2) w2h[i - n1] = f2h(w2[i - n1]);
    else if (i < n1 + n2 + ne) embh[i - n1 - n2] = f2bf(emb[i - n1 - n2]);
}

// gemm1: h1bh[16-row tile] = bf16(b1 + embh[h_ids[row]] @ bf16(lw1))   (MFMA)
__global__ __launch_bounds__(256) void
gemm1_mfma(const unsigned short* __restrict__ embh, const int* __restrict__ h_ids,
           const float* __restrict__ lw1, const float* __restrict__ b1,
           unsigned short* __restrict__ h1bh, int n_nodes) {
    int w = threadIdx.x >> 6, l = threadIdx.x & 63;
    int lr = l & 15, lq = l >> 4;
    int rt = blockIdx.x;
    bf16x8 bfr[2];
    int coln = w * 16 + lr;
#pragma unroll
    for (int kb = 0; kb < 2; ++kb)
#pragma unroll
        for (int jj = 0; jj < 8; ++jj)
            bfr[kb][jj] = (short)f2bf(lw1[(kb * 32 + lq * 8 + jj) * 64 + coln]);
    int nrow = rt * 16 + lr;
    if (nrow >= n_nodes) nrow = n_nodes - 1;
    const unsigned short* arow = embh + (long)h_ids[nrow] * 64 + lq * 8;
    bf16x8 af0 = *(const bf16x8*)arow;
    bf16x8 af1 = *(const bf16x8*)(arow + 32);
    f32x4 acc = {0.f, 0.f, 0.f, 0.f};
    acc = __builtin_amdgcn_mfma_f32_16x16x32_bf16(af0, bfr[0], acc, 0, 0, 0);
    acc = __builtin_amdgcn_mfma_f32_16x16x32_bf16(af1, bfr[1], acc, 0, 0, 0);
    float bb = b1[coln];
#pragma unroll
    for (int r = 0; r < 4; ++r) {
        int row = rt * 16 + lq * 4 + r;
        if (row < n_nodes) h1bh[(long)row * 64 + coln] = f2bf(acc[r] + bb);
    }
}

// gemm2: h2bh[16-row tile] = bf16(b2 + h1h @ bf16(lw2))  (MFMA)
__global__ __launch_bounds__(256) void
gemm2_mfma(const unsigned short* __restrict__ h1h, const float* __restrict__ lw2,
           const float* __restrict__ b2, unsigned short* __restrict__ h2bh, int n_nodes) {
    int w = threadIdx.x >> 6, l = threadIdx.x & 63;
    int lr = l & 15, lq = l >> 4;
    int rt = blockIdx.x;
    bf16x8 bfr[2][2];
    int col0 = (2 * w) * 16 + lr, col1 = (2 * w + 1) * 16 + lr;
#pragma unroll
    for (int kb = 0; kb < 2; ++kb)
#pragma unroll
        for (int jj = 0; jj < 8; ++jj) {
            int k = kb * 32 + lq * 8 + jj;
            bfr[0][kb][jj] = (short)f2bf(lw2[k * 128 + col0]);
            bfr[1][kb][jj] = (short)f2bf(lw2[k * 128 + col1]);
        }
    int nrow = rt * 16 + lr;
    if (nrow >= n_nodes) nrow = n_nodes - 1;
    bf16x8 af0 = *(const bf16x8*)(h1h + (long)nrow * 64 + lq * 8);
    bf16x8 af1 = *(const bf16x8*)(h1h + (long)nrow * 64 + 32 + lq * 8);
    f32x4 acc0 = {0.f, 0.f, 0.f, 0.f}, acc1 = {0.f, 0.f, 0.f, 0.f};
    acc0 = __builtin_amdgcn_mfma_f32_16x16x32_bf16(af0, bfr[0][0], acc0, 0, 0, 0);
    acc0 = __builtin_amdgcn_mfma_f32_16x16x32_bf16(af1, bfr[0][1], acc0, 0, 0, 0);
    acc1 = __builtin_amdgcn_mfma_f32_16x16x32_bf16(af0, bfr[1][0], acc1, 0, 0, 0);
    acc1 = __builtin_amdgcn_mfma_f32_16x16x32_bf16(af1, bfr[1][1], acc1, 0, 0, 0);
    float bb0 = b2[col0], bb1 = b2[col1];
#pragma unroll
    for (int r = 0; r < 4; ++r) {
        int row = rt * 16 + lq * 4 + r;
        if (row < n_nodes) {
            h2bh[(long)row * 128 + col0] = f2bf(acc0[r] + bb0);
            h2bh[(long)row * 128 + col1] = f2bf(acc1[r] + bb1);
        }
    }
}

// butterfly transpose-reduce over 8-lane group
__device__ __forceinline__ float reduce8(float a0, float a1, float a2, float a3,
                                         float a4, float a5, float a6, float a7, int i) {
    int p1 = i & 1, p2 = (i >> 1) & 1, p3 = (i >> 2) & 1;
    float ka, sb, u0, u1, u2, u3, w0, w1;
    ka = p1 ? a1 : a0; sb = p1 ? a0 : a1; u0 = ka + __shfl_xor(sb, 1, 64);
    ka = p1 ? a3 : a2; sb = p1 ? a2 : a3; u1 = ka + __shfl_xor(sb, 1, 64);
    ka = p1 ? a5 : a4; sb = p1 ? a4 : a5; u2 = ka + __shfl_xor(sb, 1, 64);
    ka = p1 ? a7 : a6; sb = p1 ? a6 : a7; u3 = ka + __shfl_xor(sb, 1, 64);
    ka = p2 ? u1 : u0; sb = p2 ? u0 : u1; w0 = ka + __shfl_xor(sb, 2, 64);
    ka = p2 ? u3 : u2; sb = p2 ? u2 : u3; w1 = ka + __shfl_xor(sb, 2, 64);
    ka = p3 ? w1 : w0; sb = p3 ? w0 : w1;
    return ka + __shfl_xor(sb, 4, 64);
}

// edge1: h1h[n] = bf16(relu(h1bh[n] + sum_e nm * bdd(embh[pkA], w1h[rel])))
// one node per wave; source rows staged HBM->LDS via global_load_lds
__global__ __launch_bounds__(256) void
edge1(const unsigned short* __restrict__ embh, const unsigned short* __restrict__ w1h,
      const unsigned short* __restrict__ h1bh, const int* __restrict__ off,
      const unsigned* __restrict__ packA, const float* __restrict__ norm_s,
      unsigned short* __restrict__ h1h, int n_nodes) {
    __shared__ unsigned short xstage[4][8][64];   // 1KB per wave
    int tid = threadIdx.x;
    int w = tid >> 6, j = tid & 63, i = j & 7;
    int cl = j >> 3, il = j & 7;                  // lane -> (edge cl, 16B chunk il)
    int n = blockIdx.x * 4 + w;
    if (n >= n_nodes) return;
    unsigned short* xsw = &xstage[w][0][0];
    float base = bfs(h1bh[(long)n * 64 + j]);     // issue early
    h2 acc[4];
#pragma unroll
    for (int q = 0; q < 4; ++q) acc[q] = (h2){(_Float16)0.f, (_Float16)0.f};
    int e0 = off[n], e1v = off[n + 1];
    const long woff = (long)j * 8;
    for (int win = e0; win < e1v; win += 64) {
        int wcnt = e1v - win; if (wcnt > 64) wcnt = 64;
        unsigned u = (j < wcnt) ? packA[win + j] : 0u;
        float nmv = (j < wcnt) ? norm_s[win + j] : 0.f;
        for (int b8 = 0; b8 < wcnt; b8 += 8) {
            int cnt = wcnt - b8; if (cnt > 8) cnt = 8;
            int uc = __builtin_amdgcn_ds_bpermute((b8 + cl) << 2, (int)u);
            if (cl < cnt)   // lane j -> LDS byte j*16 (HW: base + lane*16)
                gload_lds16(embh + (long)((unsigned)uc & 0xFFFFu) * 64 + (il << 3), xsw);
            asm volatile("s_waitcnt vmcnt(0)" ::: "memory");
            __builtin_amdgcn_sched_barrier(0);
#pragma unroll
            for (int c = 0; c < 8; ++c)
                if (c < cnt) {
                    float nm = bcastf(nmv, b8 + c);
                    int rr = bcasti((int)u, b8 + c) >> 16;
                    uint4 wd = *(const uint4*)(w1h + (long)rr * 512 + woff);
                    _Float16 xh = (_Float16)(bfs(xsw[(c << 6) + j]) * nm);
                    h2 xh2 = {xh, xh};
                    acc[0] += xh2 * uh2(wd.x);
                    acc[1] += xh2 * uh2(wd.y);
                    acc[2] += xh2 * uh2(wd.z);
                    acc[3] += xh2 * uh2(wd.w);
                }
        }
    }
    float agg = reduce8((float)acc[0].x, (float)acc[0].y, (float)acc[1].x, (float)acc[1].y,
                        (float)acc[2].x, (float)acc[2].y, (float)acc[3].x, (float)acc[3].y, i);
    h1h[(long)n * 64 + j] = f2bf(fmaxf(base + agg, 0.f));
}

// edge2: output-half split — each wave computes 64 of the 128 out cols.
// half = blockIdx.x & 1; lane j -> out col o = (j>>3)*16 + (j&7) + half*8.
// Identical per-output arithmetic/order to R18b (numerics unchanged).
__global__ __launch_bounds__(256) void
edge2(const unsigned short* __restrict__ h1h, const unsigned short* __restrict__ w2h,
      const unsigned short* __restrict__ h2bh, const float* __restrict__ eps,
      const int* __restrict__ off, const unsigned* __restrict__ packB,
      const float* __restrict__ norm_s, float* __restrict__ out, int n_nodes) {
    __shared__ unsigned short xstage[4][8][64];   // 1KB per wave
    int tid = threadIdx.x;
    int w = tid >> 6, j = tid & 63;
    int i = j & 7, b = j >> 3;
    int half = blockIdx.x & 1;
    int o = b * 16 + i + half * 8;                // this wave's output col
    int cl = j >> 3, il = j & 7;
    int n = (blockIdx.x >> 1) * 4 + w;
    if (n >= n_nodes) return;
    unsigned short* xsw = &xstage[w][0][0];
    float base = bfs(h2bh[(long)n * 128 + o]);    // issue early
    h2 acc[4];
#pragma unroll
    for (int q = 0; q < 4; ++q) acc[q] = (h2){(_Float16)0.f, (_Float16)0.f};
    int e0 = off[n], e1v = off[n + 1];
    const long woff = (long)j * 16 + half * 8;    // f16 offset; byte off 16B-aligned
    for (int win = e0; win < e1v; win += 64) {
        int wcnt = e1v - win; if (wcnt > 64) wcnt = 64;
        unsigned u = (j < wcnt) ? packB[win + j] : 0u;
        float nmv = (j < wcnt) ? norm_s[win + j] : 0.f;
        for (int b8 = 0; b8 < wcnt; b8 += 8) {
            int cnt = wcnt - b8; if (cnt > 8) cnt = 8;
            int uc = __builtin_amdgcn_ds_bpermute((b8 + cl) << 2, (int)u);
            if (cl < cnt)
                gload_lds16(h1h + (long)((unsigned)uc & 0xFFFFu) * 64 + (il << 3), xsw);
            asm volatile("s_waitcnt vmcnt(0)" ::: "memory");
            __builtin_amdgcn_sched_barrier(0);
#pragma unroll
            for (int c = 0; c < 8; ++c)
                if (c < cnt) {
                    float nm = bcastf(nmv, b8 + c);
                    int rr = bcasti((int)u, b8 + c) >> 16;
                    uint4 wd = *(const uint4*)(w2h + (long)rr * 1024 + woff);
                    _Float16 xh = (_Float16)(bfs(xsw[(c << 6) + j]) * nm);
                    h2 xh2 = {xh, xh};
                    acc[0] += xh2 * uh2(wd.x);
                    acc[1] += xh2 * uh2(wd.y);
                    acc[2] += xh2 * uh2(wd.z);
                    acc[3] += xh2 * uh2(wd.w);
                }
        }
    }
    float r = reduce8((float)acc[0].x, (float)acc[0].y, (float)acc[1].x, (float)acc[1].y,
                      (float)acc[2].x, (float)acc[2].y, (float)acc[3].x, (float)acc[3].y, i);
    float v = r + base;
    float p = __shfl_xor(v, 32, 64);              // lane j<32: o in m-region; j+32 holds o+64
    if (j < 32) {
        long basep = (long)n * 64;
        float sp = (p > 20.f) ? p : log1pf(expf(p));
        out[basep + o] = fmaf(sqrtf(sp + 1e-8f), eps[basep + o], v);
    }
}

extern "C" void kernel_launch(void* const* d_in, const int* in_sizes, int n_in,
                              void* d_out, int out_size, void* d_ws, size_t ws_size,
                              hipStream_t stream) {
    const float* emb   = (const float*)d_in[0];
    const float* norm  = (const float*)d_in[1];
    const float* eps   = (const float*)d_in[2];
    const float* w1    = (const float*)d_in[3];
    const float* lw1   = (const float*)d_in[4];
    const float* b1    = (const float*)d_in[5];
    const float* w2    = (const float*)d_in[6];
    const float* lw2   = (const float*)d_in[7];
    const float* b2    = (const float*)d_in[8];
    const int*   h_ids = (const int*)d_in[9];
    const int*   src   = (const int*)d_in[10];
    const int*   dst   = (const int*)d_in[11];
    const int*   rel   = (const int*)d_in[12];
    float* out = (float*)d_out;

    int n_nodes = in_sizes[0] / 64;   // 50000
    int n_edges = in_sizes[10];       // 400000
    int nw1 = in_sizes[3];            // 200*512
    int nw2 = in_sizes[6];            // 200*1024
    int ne  = in_sizes[0];            // N*64

    char* ws = (char*)d_ws;
    unsigned short* h1bh = (unsigned short*)ws;       ws += (size_t)n_nodes * 64 * 2;
    unsigned short* h1h  = (unsigned short*)ws;       ws += (size_t)n_nodes * 64 * 2;
    unsigned short* h2bh = (unsigned short*)ws;       ws += (size_t)n_nodes * 128 * 2;
    unsigned short* embh = (unsigned short*)ws;       ws += (size_t)ne * 2;
    unsigned short* w1h  = (unsigned short*)ws;       ws += (size_t)nw1 * 2;
    unsigned short* w2h  = (unsigned short*)ws;       ws += (size_t)nw2 * 2;
    unsigned* pkA = (unsigned*)ws;                    ws += (size_t)n_edges * 4;
    unsigned* pkB = (unsigned*)ws;                    ws += (size_t)n_edges * 4;
    float* norm_s = (float*)ws;                       ws += (size_t)n_edges * 4;
    int*   deg    = (int*)ws;                         ws += (size_t)n_nodes * 4;
    int*   fil    = (int*)ws;                         ws += (size_t)n_nodes * 4;
    int*   off    = (int*)ws;                         ws += (size_t)(n_nodes + 1) * 4;
    int*   bsum   = (int*)ws;

    int blk = 256;
    int nb = (n_nodes + 255) / 256;
    int nt = (n_nodes + 15) / 16;
    int ng = (n_nodes + 3) / 4;       // one node per wave (edge1)
    int ng2 = 2 * ng;                 // edge2: 2 halves, interleaved
    // CSR build + conversions
    hipMemsetAsync(deg, 0, (size_t)n_nodes * 8, stream);
    cvt_all<<<(nw1 + nw2 + ne + blk - 1) / blk, blk, 0, stream>>>(w1, w2, emb, w1h, w2h, embh, nw1, nw2, ne);
    hist<<<(n_edges + blk - 1) / blk, blk, 0, stream>>>(dst, deg, n_edges);
    scan_part<<<nb, 256, 0, stream>>>(deg, bsum, n_nodes);
    scan_bsum<<<1, 256, 0, stream>>>(bsum, off, nb, n_nodes);
    scan_write<<<nb, 256, 0, stream>>>(deg, bsum, off, n_nodes);
    scatter_pack<<<(n_edges + blk - 1) / blk, blk, 0, stream>>>(src, dst, rel, norm, h_ids, off, fil, pkA, pkB, norm_s, n_edges);
    // layer 1
    gemm1_mfma<<<nt, blk, 0, stream>>>(embh, h_ids, lw1, b1, h1bh, n_nodes);
    edge1<<<ng, blk, 0, stream>>>(embh, w1h, h1bh, off, pkA, norm_s, h1h, n_nodes);
    // layer 2
    gemm2_mfma<<<nt, blk, 0, stream>>>(h1h, lw2, b2, h2bh, n_nodes);
    edge2<<<ng2, blk, 0, stream>>>(h1h, w2h, h2bh, eps, off, pkB, norm_s, out, n_nodes);
}

// Round 11
// 264.865 us; speedup vs baseline: 1.0915x; 1.0915x over previous
//
#include <hip/hip_runtime.h>
#include <math.h>

// KGVAE: 2-layer RelGraphConv (bdd) + reparameterize, R21 = R18b (champion,
// 263.4us). Final state after full neighborhood search:
//   R19 2-node/wave: -7% | R20 out-split: -13% | rel-GEMM restructures: -15..-60%
//   f16 FMA (R13), gload_lds staging (R18b): kept, verified wins.
// Structure: dst-CSR edge walk, 1 node/wave, HBM->LDS bulk gather via
// global_load_lds(16B), f16 packed-FMA edge math, MFMA self-loop GEMMs.
// ws: h1bh | h1h | h2bh | embh | w1h(f16) | w2h(f16) | pkA | pkB | norm_s
//     | deg fil | off | bsum

typedef __attribute__((ext_vector_type(8))) short bf16x8;
typedef __attribute__((ext_vector_type(4))) float f32x4;
typedef __attribute__((ext_vector_type(2))) _Float16 h2;

__device__ __forceinline__ int bcasti(int v, int l) { return __builtin_amdgcn_readlane(v, l); }
__device__ __forceinline__ float bcastf(float v, int l) {
    return __int_as_float(__builtin_amdgcn_readlane(__float_as_int(v), l));
}
__device__ __forceinline__ unsigned short f2bf(float f) {  // RTN bf16
    unsigned u = __float_as_uint(f);
    return (unsigned short)((u + 0x7FFFu + ((u >> 16) & 1u)) >> 16);
}
__device__ __forceinline__ unsigned short f2h(float f) {   // RN f16
    return __builtin_bit_cast(unsigned short, (_Float16)f);
}
__device__ __forceinline__ float bfs(unsigned short s) { return __uint_as_float((unsigned)s << 16); }
__device__ __forceinline__ h2 uh2(unsigned u) { return __builtin_bit_cast(h2, u); }

// direct global->LDS 16B: LDS dest = base + lane*16 (HW), global addr per-lane
__device__ __forceinline__ void gload_lds16(const void* g, void* l) {
    __builtin_amdgcn_global_load_lds(
        (const __attribute__((address_space(1))) unsigned int*)g,
        (__attribute__((address_space(3))) unsigned int*)l, 16, 0, 0);
}

__global__ void hist(const int* __restrict__ dst, int* __restrict__ deg, int e) {
    int i = blockIdx.x * blockDim.x + threadIdx.x;
    if (i < e) atomicAdd(&deg[dst[i]], 1);
}

__global__ void scan_part(const int* __restrict__ deg, int* __restrict__ bsum, int n) {
    __shared__ int sm[256];
    int t = threadIdx.x, g = blockIdx.x * 256 + t;
    sm[t] = (g < n) ? deg[g] : 0;
    __syncthreads();
    for (int d = 128; d > 0; d >>= 1) {
        if (t < d) sm[t] += sm[t + d];
        __syncthreads();
    }
    if (t == 0) bsum[blockIdx.x] = sm[0];
}

__global__ void scan_bsum(int* __restrict__ bsum, int* __restrict__ off, int nb, int n) {
    __shared__ int sm[256];
    int t = threadIdx.x;
    int v = (t < nb) ? bsum[t] : 0;
    sm[t] = v;
    __syncthreads();
    for (int d = 1; d < 256; d <<= 1) {
        int u = (t >= d) ? sm[t - d] : 0;
        __syncthreads();
        sm[t] += u;
        __syncthreads();
    }
    if (t < nb) bsum[t] = sm[t] - v;
    if (t == 255) off[n] = sm[255];
}

__global__ void scan_write(const int* __restrict__ deg, const int* __restrict__ bsum,
                           int* __restrict__ off, int n) {
    __shared__ int sm[256];
    int t = threadIdx.x, g = blockIdx.x * 256 + t;
    int v = (g < n) ? deg[g] : 0;
    sm[t] = v;
    __syncthreads();
    for (int d = 1; d < 256; d <<= 1) {
        int u = (t >= d) ? sm[t - d] : 0;
        __syncthreads();
        sm[t] += u;
        __syncthreads();
    }
    if (g < n) off[g] = bsum[blockIdx.x] + sm[t] - v;
}

__global__ void scatter_pack(const int* __restrict__ src, const int* __restrict__ dst,
                             const int* __restrict__ rel, const float* __restrict__ norm,
                             const int* __restrict__ h_ids, const int* __restrict__ off,
                             int* __restrict__ fil, unsigned* __restrict__ packA,
                             unsigned* __restrict__ packB, float* __restrict__ norm_s, int e) {
    int i = blockIdx.x * blockDim.x + threadIdx.x;
    if (i >= e) return;
    int d = dst[i];
    int p = off[d] + atomicAdd(&fil[d], 1);
    unsigned rhi = (unsigned)rel[i] << 16;
    int s = src[i];
    packA[p] = (unsigned)h_ids[s] | rhi;
    packB[p] = (unsigned)s | rhi;
    norm_s[p] = norm[i];
}

// fused conversion: w1,w2 -> f16 ; emb -> bf16
__global__ void cvt_all(const float* __restrict__ w1, const float* __restrict__ w2,
                        const float* __restrict__ emb, unsigned short* __restrict__ w1h,
                        unsigned short* __restrict__ w2h, unsigned short* __restrict__ embh,
                        int n1, int n2, int ne) {
    int i = blockIdx.x * blockDim.x + threadIdx.x;
    if (i < n1) w1h[i] = f2h(w1[i]);
    else if (i < n1 + n2) w2h[i - n1] = f2h(w2[i - n1]);
    else if (i < n1 + n2 + ne) embh[i - n1 - n2] = f2bf(emb[i - n1 - n2]);
}

// gemm1: h1bh[16-row tile] = bf16(b1 + embh[h_ids[row]] @ bf16(lw1))   (MFMA)
__global__ __launch_bounds__(256) void
gemm1_mfma(const unsigned short* __restrict__ embh, const int* __restrict__ h_ids,
           const float* __restrict__ lw1, const float* __restrict__ b1,
           unsigned short* __restrict__ h1bh, int n_nodes) {
    int w = threadIdx.x >> 6, l = threadIdx.x & 63;
    int lr = l & 15, lq = l >> 4;
    int rt = blockIdx.x;
    bf16x8 bfr[2];
    int coln = w * 16 + lr;
#pragma unroll
    for (int kb = 0; kb < 2; ++kb)
#pragma unroll
        for (int jj = 0; jj < 8; ++jj)
            bfr[kb][jj] = (short)f2bf(lw1[(kb * 32 + lq * 8 + jj) * 64 + coln]);
    int nrow = rt * 16 + lr;
    if (nrow >= n_nodes) nrow = n_nodes - 1;
    const unsigned short* arow = embh + (long)h_ids[nrow] * 64 + lq * 8;
    bf16x8 af0 = *(const bf16x8*)arow;
    bf16x8 af1 = *(const bf16x8*)(arow + 32);
    f32x4 acc = {0.f, 0.f, 0.f, 0.f};
    acc = __builtin_amdgcn_mfma_f32_16x16x32_bf16(af0, bfr[0], acc, 0, 0, 0);
    acc = __builtin_amdgcn_mfma_f32_16x16x32_bf16(af1, bfr[1], acc, 0, 0, 0);
    float bb = b1[coln];
#pragma unroll
    for (int r = 0; r < 4; ++r) {
        int row = rt * 16 + lq * 4 + r;
        if (row < n_nodes) h1bh[(long)row * 64 + coln] = f2bf(acc[r] + bb);
    }
}

// gemm2: h2bh[16-row tile] = bf16(b2 + h1h @ bf16(lw2))  (MFMA)
__global__ __launch_bounds__(256) void
gemm2_mfma(const unsigned short* __restrict__ h1h, const float* __restrict__ lw2,
           const float* __restrict__ b2, unsigned short* __restrict__ h2bh, int n_nodes) {
    int w = threadIdx.x >> 6, l = threadIdx.x & 63;
    int lr = l & 15, lq = l >> 4;
    int rt = blockIdx.x;
    bf16x8 bfr[2][2];
    int col0 = (2 * w) * 16 + lr, col1 = (2 * w + 1) * 16 + lr;
#pragma unroll
    for (int kb = 0; kb < 2; ++kb)
#pragma unroll
        for (int jj = 0; jj < 8; ++jj) {
            int k = kb * 32 + lq * 8 + jj;
            bfr[0][kb][jj] = (short)f2bf(lw2[k * 128 + col0]);
            bfr[1][kb][jj] = (short)f2bf(lw2[k * 128 + col1]);
        }
    int nrow = rt * 16 + lr;
    if (nrow >= n_nodes) nrow = n_nodes - 1;
    bf16x8 af0 = *(const bf16x8*)(h1h + (long)nrow * 64 + lq * 8);
    bf16x8 af1 = *(const bf16x8*)(h1h + (long)nrow * 64 + 32 + lq * 8);
    f32x4 acc0 = {0.f, 0.f, 0.f, 0.f}, acc1 = {0.f, 0.f, 0.f, 0.f};
    acc0 = __builtin_amdgcn_mfma_f32_16x16x32_bf16(af0, bfr[0][0], acc0, 0, 0, 0);
    acc0 = __builtin_amdgcn_mfma_f32_16x16x32_bf16(af1, bfr[0][1], acc0, 0, 0, 0);
    acc1 = __builtin_amdgcn_mfma_f32_16x16x32_bf16(af0, bfr[1][0], acc1, 0, 0, 0);
    acc1 = __builtin_amdgcn_mfma_f32_16x16x32_bf16(af1, bfr[1][1], acc1, 0, 0, 0);
    float bb0 = b2[col0], bb1 = b2[col1];
#pragma unroll
    for (int r = 0; r < 4; ++r) {
        int row = rt * 16 + lq * 4 + r;
        if (row < n_nodes) {
            h2bh[(long)row * 128 + col0] = f2bf(acc0[r] + bb0);
            h2bh[(long)row * 128 + col1] = f2bf(acc1[r] + bb1);
        }
    }
}

// butterfly transpose-reduce over 8-lane group
__device__ __forceinline__ float reduce8(float a0, float a1, float a2, float a3,
                                         float a4, float a5, float a6, float a7, int i) {
    int p1 = i & 1, p2 = (i >> 1) & 1, p3 = (i >> 2) & 1;
    float ka, sb, u0, u1, u2, u3, w0, w1;
    ka = p1 ? a1 : a0; sb = p1 ? a0 : a1; u0 = ka + __shfl_xor(sb, 1, 64);
    ka = p1 ? a3 : a2; sb = p1 ? a2 : a3; u1 = ka + __shfl_xor(sb, 1, 64);
    ka = p1 ? a5 : a4; sb = p1 ? a4 : a5; u2 = ka + __shfl_xor(sb, 1, 64);
    ka = p1 ? a7 : a6; sb = p1 ? a6 : a7; u3 = ka + __shfl_xor(sb, 1, 64);
    ka = p2 ? u1 : u0; sb = p2 ? u0 : u1; w0 = ka + __shfl_xor(sb, 2, 64);
    ka = p2 ? u3 : u2; sb = p2 ? u2 : u3; w1 = ka + __shfl_xor(sb, 2, 64);
    ka = p3 ? w1 : w0; sb = p3 ? w0 : w1;
    return ka + __shfl_xor(sb, 4, 64);
}

// edge1: h1h[n] = bf16(relu(h1bh[n] + sum_e nm * bdd(embh[pkA], w1h[rel])))
// one node per wave; source rows staged HBM->LDS via global_load_lds
__global__ __launch_bounds__(256) void
edge1(const unsigned short* __restrict__ embh, const unsigned short* __restrict__ w1h,
      const unsigned short* __restrict__ h1bh, const int* __restrict__ off,
      const unsigned* __restrict__ packA, const float* __restrict__ norm_s,
      unsigned short* __restrict__ h1h, int n_nodes) {
    __shared__ unsigned short xstage[4][8][64];   // 1KB per wave
    int tid = threadIdx.x;
    int w = tid >> 6, j = tid & 63, i = j & 7;
    int cl = j >> 3, il = j & 7;                  // lane -> (edge cl, 16B chunk il)
    int n = blockIdx.x * 4 + w;
    if (n >= n_nodes) return;
    unsigned short* xsw = &xstage[w][0][0];
    float base = bfs(h1bh[(long)n * 64 + j]);     // issue early
    h2 acc[4];
#pragma unroll
    for (int q = 0; q < 4; ++q) acc[q] = (h2){(_Float16)0.f, (_Float16)0.f};
    int e0 = off[n], e1v = off[n + 1];
    const long woff = (long)j * 8;
    for (int win = e0; win < e1v; win += 64) {
        int wcnt = e1v - win; if (wcnt > 64) wcnt = 64;
        unsigned u = (j < wcnt) ? packA[win + j] : 0u;
        float nmv = (j < wcnt) ? norm_s[win + j] : 0.f;
        for (int b8 = 0; b8 < wcnt; b8 += 8) {
            int cnt = wcnt - b8; if (cnt > 8) cnt = 8;
            int uc = __builtin_amdgcn_ds_bpermute((b8 + cl) << 2, (int)u);
            if (cl < cnt)   // lane j -> LDS byte j*16 (HW: base + lane*16)
                gload_lds16(embh + (long)((unsigned)uc & 0xFFFFu) * 64 + (il << 3), xsw);
            asm volatile("s_waitcnt vmcnt(0)" ::: "memory");
            __builtin_amdgcn_sched_barrier(0);
#pragma unroll
            for (int c = 0; c < 8; ++c)
                if (c < cnt) {
                    float nm = bcastf(nmv, b8 + c);
                    int rr = bcasti((int)u, b8 + c) >> 16;
                    uint4 wd = *(const uint4*)(w1h + (long)rr * 512 + woff);
                    _Float16 xh = (_Float16)(bfs(xsw[(c << 6) + j]) * nm);
                    h2 xh2 = {xh, xh};
                    acc[0] += xh2 * uh2(wd.x);
                    acc[1] += xh2 * uh2(wd.y);
                    acc[2] += xh2 * uh2(wd.z);
                    acc[3] += xh2 * uh2(wd.w);
                }
        }
    }
    float agg = reduce8((float)acc[0].x, (float)acc[0].y, (float)acc[1].x, (float)acc[1].y,
                        (float)acc[2].x, (float)acc[2].y, (float)acc[3].x, (float)acc[3].y, i);
    h1h[(long)n * 64 + j] = f2bf(fmaxf(base + agg, 0.f));
}

// edge2: out = reparam(h2bh[n] + sum_e nm * bdd(h1h[src], w2h[rel]))
__global__ __launch_bounds__(256) void
edge2(const unsigned short* __restrict__ h1h, const unsigned short* __restrict__ w2h,
      const unsigned short* __restrict__ h2bh, const float* __restrict__ eps,
      const int* __restrict__ off, const unsigned* __restrict__ packB,
      const float* __restrict__ norm_s, float* __restrict__ out, int n_nodes) {
    __shared__ unsigned short xstage[4][8][64];   // 1KB per wave
    int tid = threadIdx.x;
    int w = tid >> 6, j = tid & 63;
    int i = j & 7, b = j >> 3;
    int o1 = b * 16 + i, o2 = o1 + 8;
    int cl = j >> 3, il = j & 7;
    int n = blockIdx.x * 4 + w;
    if (n >= n_nodes) return;
    unsigned short* xsw = &xstage[w][0][0];
    float base1 = bfs(h2bh[(long)n * 128 + o1]);  // issue early
    float base2 = bfs(h2bh[(long)n * 128 + o2]);
    h2 acc[8];
#pragma unroll
    for (int q = 0; q < 8; ++q) acc[q] = (h2){(_Float16)0.f, (_Float16)0.f};
    int e0 = off[n], e1v = off[n + 1];
    const long woff = (long)j * 16;
    for (int win = e0; win < e1v; win += 64) {
        int wcnt = e1v - win; if (wcnt > 64) wcnt = 64;
        unsigned u = (j < wcnt) ? packB[win + j] : 0u;
        float nmv = (j < wcnt) ? norm_s[win + j] : 0.f;
        for (int b8 = 0; b8 < wcnt; b8 += 8) {
            int cnt = wcnt - b8; if (cnt > 8) cnt = 8;
            int uc = __builtin_amdgcn_ds_bpermute((b8 + cl) << 2, (int)u);
            if (cl < cnt)
                gload_lds16(h1h + (long)((unsigned)uc & 0xFFFFu) * 64 + (il << 3), xsw);
            asm volatile("s_waitcnt vmcnt(0)" ::: "memory");
            __builtin_amdgcn_sched_barrier(0);
#pragma unroll
            for (int c = 0; c < 8; ++c)
                if (c < cnt) {
                    float nm = bcastf(nmv, b8 + c);
                    int rr = bcasti((int)u, b8 + c) >> 16;
                    const uint4* p = (const uint4*)(w2h + (long)rr * 1024 + woff);
                    uint4 wa = p[0], wb = p[1];
                    _Float16 xh = (_Float16)(bfs(xsw[(c << 6) + j]) * nm);
                    h2 xh2 = {xh, xh};
                    acc[0] += xh2 * uh2(wa.x);
                    acc[1] += xh2 * uh2(wa.y);
                    acc[2] += xh2 * uh2(wa.z);
                    acc[3] += xh2 * uh2(wa.w);
                    acc[4] += xh2 * uh2(wb.x);
                    acc[5] += xh2 * uh2(wb.y);
                    acc[6] += xh2 * uh2(wb.z);
                    acc[7] += xh2 * uh2(wb.w);
                }
        }
    }
    float r1 = reduce8((float)acc[0].x, (float)acc[0].y, (float)acc[1].x, (float)acc[1].y,
                       (float)acc[2].x, (float)acc[2].y, (float)acc[3].x, (float)acc[3].y, i);
    float r2 = reduce8((float)acc[4].x, (float)acc[4].y, (float)acc[5].x, (float)acc[5].y,
                       (float)acc[6].x, (float)acc[6].y, (float)acc[7].x, (float)acc[7].y, i);
    float v1 = r1 + base1;
    float v2 = r2 + base2;
    float p1 = __shfl_xor(v1, 32, 64);
    float p2 = __shfl_xor(v2, 32, 64);
    if (j < 32) {
        long basep = (long)n * 64;
        float sp1 = (p1 > 20.f) ? p1 : log1pf(expf(p1));
        float sp2 = (p2 > 20.f) ? p2 : log1pf(expf(p2));
        out[basep + o1] = fmaf(sqrtf(sp1 + 1e-8f), eps[basep + o1], v1);
        out[basep + o2] = fmaf(sqrtf(sp2 + 1e-8f), eps[basep + o2], v2);
    }
}

extern "C" void kernel_launch(void* const* d_in, const int* in_sizes, int n_in,
                              void* d_out, int out_size, void* d_ws, size_t ws_size,
                              hipStream_t stream) {
    const float* emb   = (const float*)d_in[0];
    const float* norm  = (const float*)d_in[1];
    const float* eps   = (const float*)d_in[2];
    const float* w1    = (const float*)d_in[3];
    const float* lw1   = (const float*)d_in[4];
    const float* b1    = (const float*)d_in[5];
    const float* w2    = (const float*)d_in[6];
    const float* lw2   = (const float*)d_in[7];
    const float* b2    = (const float*)d_in[8];
    const int*   h_ids = (const int*)d_in[9];
    const int*   src   = (const int*)d_in[10];
    const int*   dst   = (const int*)d_in[11];
    const int*   rel   = (const int*)d_in[12];
    float* out = (float*)d_out;

    int n_nodes = in_sizes[0] / 64;   // 50000
    int n_edges = in_sizes[10];       // 400000
    int nw1 = in_sizes[3];            // 200*512
    int nw2 = in_sizes[6];            // 200*1024
    int ne  = in_sizes[0];            // N*64

    char* ws = (char*)d_ws;
    unsigned short* h1bh = (unsigned short*)ws;       ws += (size_t)n_nodes * 64 * 2;
    unsigned short* h1h  = (unsigned short*)ws;       ws += (size_t)n_nodes * 64 * 2;
    unsigned short* h2bh = (unsigned short*)ws;       ws += (size_t)n_nodes * 128 * 2;
    unsigned short* embh = (unsigned short*)ws;       ws += (size_t)ne * 2;
    unsigned short* w1h  = (unsigned short*)ws;       ws += (size_t)nw1 * 2;
    unsigned short* w2h  = (unsigned short*)ws;       ws += (size_t)nw2 * 2;
    unsigned* pkA = (unsigned*)ws;                    ws += (size_t)n_edges * 4;
    unsigned* pkB = (unsigned*)ws;                    ws += (size_t)n_edges * 4;
    float* norm_s = (float*)ws;                       ws += (size_t)n_edges * 4;
    int*   deg    = (int*)ws;                         ws += (size_t)n_nodes * 4;
    int*   fil    = (int*)ws;                         ws += (size_t)n_nodes * 4;
    int*   off    = (int*)ws;                         ws += (size_t)(n_nodes + 1) * 4;
    int*   bsum   = (int*)ws;

    int blk = 256;
    int nb = (n_nodes + 255) / 256;
    int nt = (n_nodes + 15) / 16;
    int ng = (n_nodes + 3) / 4;       // one node per wave
    // CSR build + conversions
    hipMemsetAsync(deg, 0, (size_t)n_nodes * 8, stream);
    cvt_all<<<(nw1 + nw2 + ne + blk - 1) / blk, blk, 0, stream>>>(w1, w2, emb, w1h, w2h, embh, nw1, nw2, ne);
    hist<<<(n_edges + blk - 1) / blk, blk, 0, stream>>>(dst, deg, n_edges);
    scan_part<<<nb, 256, 0, stream>>>(deg, bsum, n_nodes);
    scan_bsum<<<1, 256, 0, stream>>>(bsum, off, nb, n_nodes);
    scan_write<<<nb, 256, 0, stream>>>(deg, bsum, off, n_nodes);
    scatter_pack<<<(n_edges + blk - 1) / blk, blk, 0, stream>>>(src, dst, rel, norm, h_ids, off, fil, pkA, pkB, norm_s, n_edges);
    // layer 1
    gemm1_mfma<<<nt, blk, 0, stream>>>(embh, h_ids, lw1, b1, h1bh, n_nodes);
    edge1<<<ng, blk, 0, stream>>>(embh, w1h, h1bh, off, pkA, norm_s, h1h, n_nodes);
    // layer 2
    gemm2_mfma<<<nt, blk, 0, stream>>>(h1h, lw2, b2, h2bh, n_nodes);
    edge2<<<ng, blk, 0, stream>>>(h1h, w2h, h2bh, eps, off, pkB, norm_s, out, n_nodes);
}